// Round 1
// baseline (83.254 us; speedup 1.0000x reference)
//
#include <hip/hip_runtime.h>

// Q8_0-style fused dequant + linear: y[32,11008] = x[32,4096] @ W^T + bias
// W[o,i] = (qweight[o,i] - 127) * scales[o, i/32]
//
// Strategy: fp32 LDS-tiled GEMM. Block tile M=32(all b) x N=64 o's,
// K split x4 across blocks (atomicAdd combine; out pre-init'd with bias).
// Dequant happens once per weight during LDS staging (2 VALU/weight).

#define O_DIM 11008
#define I_DIM 4096
#define NB    (I_DIM / 32)   // scale blocks per row = 128
#define B_DIM 32
#define NT    64             // outputs per block
#define KT    1024           // K-range per block (I_DIM / 4)
#define KS    128            // K-step staged per iteration
#define XPAD  36             // x_s row stride (floats): 16B-aligned rows, breaks pow2 banks
#define WPAD  66             // w_s row stride (floats): 8B-aligned rows, 2-way read conflicts only

__global__ __launch_bounds__(256) void init_out_kernel(const float* __restrict__ bias,
                                                       float* __restrict__ out) {
    const int o = blockIdx.x * 256 + threadIdx.x;   // grid.x = O_DIM/256 = 43
    const int b = blockIdx.y;                        // grid.y = 32
    out[b * O_DIM + o] = bias[o];
}

__global__ __launch_bounds__(256) void gemm_dq_kernel(const float* __restrict__ x,
                                                      const int*   __restrict__ qw,
                                                      const float* __restrict__ scales,
                                                      float*       __restrict__ out) {
    __shared__ float w_s[KS][WPAD];   // [k][o]  dequantized
    __shared__ float x_s[KS][XPAD];   // [k][b]  transposed

    const int t      = threadIdx.x;
    const int o_base = blockIdx.x * NT;   // 0..171 tiles
    const int k_base = blockIdx.y * KT;   // 0..3 K-splits

    const int wav = t >> 6;     // wave id 0..3
    const int lan = t & 63;     // lane

    // compute-phase mapping: thread tile = 4 b's x 2 o's
    const int og = t & 31;      // o pair index
    const int bg = t >> 5;      // b quad index (0..7)
    const int o0 = og * 2;
    const int b0 = bg * 4;

    // x staging mapping: thread covers 16 consecutive k of one b-row
    const int xb = t >> 3;            // 0..31
    const int xk = (t & 7) * 16;      // 0..112

    float acc00 = 0.f, acc01 = 0.f, acc10 = 0.f, acc11 = 0.f;
    float acc20 = 0.f, acc21 = 0.f, acc30 = 0.f, acc31 = 0.f;

    for (int ks = 0; ks < KT; ks += KS) {
        const int kg = k_base + ks;

        // ---- stage x: global [b][k] -> LDS [k][b], float4 coalesced reads ----
        {
            const float4* xsrc = reinterpret_cast<const float4*>(&x[xb * I_DIM + kg + xk]);
#pragma unroll
            for (int j = 0; j < 4; ++j) {
                const float4 v = xsrc[j];
                const int kk = xk + j * 4;
                x_s[kk + 0][xb] = v.x;
                x_s[kk + 1][xb] = v.y;
                x_s[kk + 2][xb] = v.z;
                x_s[kk + 3][xb] = v.w;
            }
        }

        // ---- stage W: dequant int32 pairs -> LDS [k][o] ----
        // wave `wav` stages rows [wav*16, wav*16+16); lane covers k-pair lan*2
        {
            const int k2 = kg + lan * 2;
            const int sk = k2 >> 5;     // scale block index along I
#pragma unroll
            for (int r = 0; r < 16; ++r) {
                const int ol = wav * 16 + r;
                const int o  = o_base + ol;
                const int2  q = *reinterpret_cast<const int2*>(&qw[o * I_DIM + k2]);
                const float s = scales[o * NB + sk];
                const float c = -127.0f * s;
                w_s[lan * 2 + 0][ol] = fmaf((float)q.x, s, c);
                w_s[lan * 2 + 1][ol] = fmaf((float)q.y, s, c);
            }
        }

        __syncthreads();

        // ---- compute: 8 FMAs per k per thread ----
#pragma unroll 8
        for (int kk = 0; kk < KS; ++kk) {
            const float4 xv = *reinterpret_cast<const float4*>(&x_s[kk][b0]);
            const float2 wv = *reinterpret_cast<const float2*>(&w_s[kk][o0]);
            acc00 = fmaf(xv.x, wv.x, acc00);
            acc01 = fmaf(xv.x, wv.y, acc01);
            acc10 = fmaf(xv.y, wv.x, acc10);
            acc11 = fmaf(xv.y, wv.y, acc11);
            acc20 = fmaf(xv.z, wv.x, acc20);
            acc21 = fmaf(xv.z, wv.y, acc21);
            acc30 = fmaf(xv.w, wv.x, acc30);
            acc31 = fmaf(xv.w, wv.y, acc31);
        }

        __syncthreads();
    }

    // ---- epilogue: combine K-split partials ----
    const int oo = o_base + o0;
    atomicAdd(&out[(b0 + 0) * O_DIM + oo + 0], acc00);
    atomicAdd(&out[(b0 + 0) * O_DIM + oo + 1], acc01);
    atomicAdd(&out[(b0 + 1) * O_DIM + oo + 0], acc10);
    atomicAdd(&out[(b0 + 1) * O_DIM + oo + 1], acc11);
    atomicAdd(&out[(b0 + 2) * O_DIM + oo + 0], acc20);
    atomicAdd(&out[(b0 + 2) * O_DIM + oo + 1], acc21);
    atomicAdd(&out[(b0 + 3) * O_DIM + oo + 0], acc30);
    atomicAdd(&out[(b0 + 3) * O_DIM + oo + 1], acc31);
}

extern "C" void kernel_launch(void* const* d_in, const int* in_sizes, int n_in,
                              void* d_out, int out_size, void* d_ws, size_t ws_size,
                              hipStream_t stream) {
    const float* x      = (const float*)d_in[0];
    const int*   qw     = (const int*)d_in[1];
    const float* scales = (const float*)d_in[2];
    const float* bias   = (const float*)d_in[3];
    float*       out    = (float*)d_out;

    // 1) out = bias (row-broadcast); also resets any poison each call
    hipLaunchKernelGGL(init_out_kernel, dim3(O_DIM / 256, B_DIM), dim3(256), 0, stream,
                       bias, out);

    // 2) fused dequant-GEMM, K-split partials accumulated atomically
    hipLaunchKernelGGL(gemm_dq_kernel, dim3(O_DIM / NT, I_DIM / KT), dim3(256), 0, stream,
                       x, qw, scales, out);
}

// Round 2
// 50.263 us; speedup vs baseline: 1.6564x; 1.6564x over previous
//
#include <hip/hip_runtime.h>
#include <hip/hip_bf16.h>

// Q8_0-style fused dequant + linear: y[32,11008] = x[32,4096] @ W^T + bias
// W[o,i] = (qweight[o,i] - 127) * scales[o, i/32]
//
// Round 2: bf16 MFMA (16x16x32) GEMM. Dequant int32->bf16 during LDS staging.
// Block tile M=32 x N=64, K-split x4 (atomicAdd f32, out pre-init with bias).
// LDS tiles XOR-swizzled (byte ^= (row&7)<<4) for conflict-free ds_read_b128.

#define O_DIM 11008
#define I_DIM 4096
#define NB    128            // I_DIM / 32 scale blocks per row
#define B_DIM 32
#define NT    64             // outputs per block
#define KT    1024           // K-range per block (I_DIM / 4)
#define KS    128            // K staged per iteration

typedef __attribute__((ext_vector_type(8))) short bf16x8;
typedef __attribute__((ext_vector_type(4))) float f32x4;

static __device__ __forceinline__ unsigned short f2bf(float f) {
    __hip_bfloat16 h = __float2bfloat16(f);
    return __builtin_bit_cast(unsigned short, h);
}

// out = bias (row broadcast) AND x -> bf16 into d_ws.
// grid = 1376 x 256 covers out (352256); first 32768 threads also convert x
// (4 floats each = 131072 elems).
__global__ __launch_bounds__(256) void init_kernel(const float* __restrict__ x,
                                                   const float* __restrict__ bias,
                                                   float* __restrict__ out,
                                                   unsigned short* __restrict__ xbf) {
    const int gid = blockIdx.x * 256 + threadIdx.x;
    const int b = gid / O_DIM;
    const int o = gid - b * O_DIM;
    out[gid] = bias[o];
    if (gid < (B_DIM * I_DIM) / 4) {
        const float4 v = reinterpret_cast<const float4*>(x)[gid];
        ushort4 u;
        u.x = f2bf(v.x); u.y = f2bf(v.y); u.z = f2bf(v.z); u.w = f2bf(v.w);
        reinterpret_cast<ushort4*>(xbf)[gid] = u;
    }
}

__global__ __launch_bounds__(256) void gemm_mfma_kernel(const unsigned short* __restrict__ xbf,
                                                        const int*   __restrict__ qw,
                                                        const float* __restrict__ scales,
                                                        float*       __restrict__ out) {
    __shared__ unsigned short w_s[NT * KS];    // [o][k] bf16, swizzled, 16 KB
    __shared__ unsigned short x_s[B_DIM * KS]; // [m][k] bf16, swizzled, 8 KB

    const int t      = threadIdx.x;
    const int wav    = t >> 6;
    const int lan    = t & 63;
    const int o_base = blockIdx.x * NT;   // 172 tiles
    const int k_base = blockIdx.y * KT;   // 4 K-splits

    // W staging: thread covers o-row `so`, 32 k's at offset `sk`
    const int so = t >> 2;
    const int sk = (t & 3) * 32;

    // compute-phase fragment indices
    const int n0   = wav * 16;       // wave's o-slice
    const int lrow = lan & 15;
    const int lq   = lan >> 4;       // lane quarter: k-group
    const int swz  = (lrow & 7) << 4;

    f32x4 acc0 = {0.f, 0.f, 0.f, 0.f};  // m rows 0..15
    f32x4 acc1 = {0.f, 0.f, 0.f, 0.f};  // m rows 16..31

    for (int ks = 0; ks < KT; ks += KS) {
        const int kg = k_base + ks;

        // ---- stage x: [32][128] bf16, b128 loads from pre-converted xbf ----
#pragma unroll
        for (int j = 0; j < 2; ++j) {
            const int idx = t + j * 256;         // 0..511
            const int m   = idx >> 4;            // 0..31
            const int kc  = (idx & 15) * 8;      // 0..120
            const bf16x8 v = *reinterpret_cast<const bf16x8*>(&xbf[m * I_DIM + kg + kc]);
            const int addr = ((m * KS + kc) * 2) ^ ((m & 7) << 4);
            *reinterpret_cast<bf16x8*>(reinterpret_cast<char*>(x_s) + addr) = v;
        }

        // ---- stage W: dequant 32 int32 -> bf16, 4x ds_write_b128 ----
        {
            const int   o = o_base + so;
            const float s = scales[o * NB + ((kg + sk) >> 5)];
            const float c = -127.0f * s;
            const int4* src = reinterpret_cast<const int4*>(&qw[o * I_DIM + kg + sk]);
#pragma unroll
            for (int ch = 0; ch < 4; ++ch) {
                const int4 qa = src[ch * 2 + 0];
                const int4 qb = src[ch * 2 + 1];
                bf16x8 v;
                v[0] = (short)f2bf(fmaf((float)qa.x, s, c));
                v[1] = (short)f2bf(fmaf((float)qa.y, s, c));
                v[2] = (short)f2bf(fmaf((float)qa.z, s, c));
                v[3] = (short)f2bf(fmaf((float)qa.w, s, c));
                v[4] = (short)f2bf(fmaf((float)qb.x, s, c));
                v[5] = (short)f2bf(fmaf((float)qb.y, s, c));
                v[6] = (short)f2bf(fmaf((float)qb.z, s, c));
                v[7] = (short)f2bf(fmaf((float)qb.w, s, c));
                const int addr = ((so * KS + sk + ch * 8) * 2) ^ ((so & 7) << 4);
                *reinterpret_cast<bf16x8*>(reinterpret_cast<char*>(w_s) + addr) = v;
            }
        }

        __syncthreads();

        // ---- compute: 4 k-steps x (2 m-frags) MFMA ----
#pragma unroll
        for (int k4 = 0; k4 < 4; ++k4) {
            const int kb = k4 * 32 + lq * 8;     // element offset in k
            const int a0addr = ((lrow * KS + kb) * 2) ^ swz;
            const int a1addr = (((lrow + 16) * KS + kb) * 2) ^ swz;  // (lrow+16)&7 == lrow&7
            const int baddr  = (((n0 + lrow) * KS + kb) * 2) ^ swz;
            const bf16x8 a0 = *reinterpret_cast<const bf16x8*>(reinterpret_cast<const char*>(x_s) + a0addr);
            const bf16x8 a1 = *reinterpret_cast<const bf16x8*>(reinterpret_cast<const char*>(x_s) + a1addr);
            const bf16x8 bb = *reinterpret_cast<const bf16x8*>(reinterpret_cast<const char*>(w_s) + baddr);
            acc0 = __builtin_amdgcn_mfma_f32_16x16x32_bf16(a0, bb, acc0, 0, 0, 0);
            acc1 = __builtin_amdgcn_mfma_f32_16x16x32_bf16(a1, bb, acc1, 0, 0, 0);
        }

        __syncthreads();
    }

    // ---- epilogue: C/D layout col=lane&15, row=(lane>>4)*4+reg (m89) ----
    const int oc = o_base + n0 + lrow;
#pragma unroll
    for (int r = 0; r < 4; ++r) {
        const int m = lq * 4 + r;
        atomicAdd(&out[m * O_DIM + oc],          acc0[r]);
        atomicAdd(&out[(m + 16) * O_DIM + oc],   acc1[r]);
    }
}

extern "C" void kernel_launch(void* const* d_in, const int* in_sizes, int n_in,
                              void* d_out, int out_size, void* d_ws, size_t ws_size,
                              hipStream_t stream) {
    const float* x      = (const float*)d_in[0];
    const int*   qw     = (const int*)d_in[1];
    const float* scales = (const float*)d_in[2];
    const float* bias   = (const float*)d_in[3];
    float*       out    = (float*)d_out;
    unsigned short* xbf = (unsigned short*)d_ws;

    // 1) out = bias; x -> bf16 scratch
    hipLaunchKernelGGL(init_kernel, dim3((B_DIM * O_DIM) / 256), dim3(256), 0, stream,
                       x, bias, out, xbf);

    // 2) fused dequant + bf16-MFMA GEMM, K-split x4 via atomicAdd
    hipLaunchKernelGGL(gemm_mfma_kernel, dim3(O_DIM / NT, I_DIM / KT), dim3(256), 0, stream,
                       xbf, qw, scales, out);
}